// Round 2
// baseline (1719.576 us; speedup 1.0000x reference)
//
#include <hip/hip_runtime.h>
#include <stdint.h>
#include <stddef.h>

#define BB 64
#define DIN 1024
#define DD 768
#define CC 1000
#define EPSA 0.1f
#define NSIM 3

// ---------------------------------------------------------------- zero amax
__global__ __launch_bounds__(256) void zero_amax_kernel(unsigned long long* __restrict__ amax) {
  int i = blockIdx.x * 256 + threadIdx.x;
  if (i < BB * CC) amax[i] = 0ull;
}

// ---------------------------------------------------------------- emb = x @ W_emb^T + b_emb   [64,768]
__global__ __launch_bounds__(256) void emb_kernel(const float* __restrict__ x,
                                                  const float* __restrict__ W_emb,
                                                  const float* __restrict__ b_emb,
                                                  float* __restrict__ emb) {
  int b = blockIdx.x;
  int d = blockIdx.y * 256 + threadIdx.x;   // gridDim.y = 3 -> d in [0,768)
  __shared__ float xs[DIN];
  for (int k = threadIdx.x; k < DIN; k += 256) xs[k] = x[b * DIN + k];
  __syncthreads();
  const float4* wr = (const float4*)(W_emb + (size_t)d * DIN);
  float acc = 0.f;
  #pragma unroll 4
  for (int k4 = 0; k4 < DIN / 4; ++k4) {
    float4 w = wr[k4];
    acc += xs[4*k4+0]*w.x + xs[4*k4+1]*w.y + xs[4*k4+2]*w.z + xs[4*k4+3]*w.w;
  }
  emb[b * DD + d] = acc + b_emb[d];
}

// ---------------------------------------------------------------- logits = emb @ W_fc^T + b_fc  [64,1000]
__global__ __launch_bounds__(256) void logits_kernel(const float* __restrict__ emb,
                                                     const float* __restrict__ W_fc,
                                                     const float* __restrict__ b_fc,
                                                     float* __restrict__ logits) {
  int b = blockIdx.x;
  int c = blockIdx.y * 256 + threadIdx.x;   // gridDim.y = 4 -> up to 1024
  __shared__ float es[DD];
  for (int k = threadIdx.x; k < DD; k += 256) es[k] = emb[b * DD + k];
  __syncthreads();
  if (c >= CC) return;
  const float4* wr = (const float4*)(W_fc + (size_t)c * DD);
  float acc = 0.f;
  #pragma unroll 4
  for (int k4 = 0; k4 < DD / 4; ++k4) {
    float4 w = wr[k4];
    acc += es[4*k4+0]*w.x + es[4*k4+1]*w.y + es[4*k4+2]*w.z + es[4*k4+3]*w.w;
  }
  logits[b * CC + c] = acc + b_fc[c];
}

// ---------------------------------------------------------------- softmax + argmax(logits)  per row
__global__ __launch_bounds__(256) void softmax_kernel(const float* __restrict__ logits,
                                                      float* __restrict__ p,
                                                      int* __restrict__ pred) {
  int b = blockIdx.x, t = threadIdx.x;
  __shared__ float smax[256];
  __shared__ int   sidx[256];
  __shared__ float ssum[256];
  float m = -3.402823466e38f; int mi = 0;
  for (int c = t; c < CC; c += 256) {
    float v = logits[b * CC + c];
    if (v > m) { m = v; mi = c; }
  }
  smax[t] = m; sidx[t] = mi;
  __syncthreads();
  for (int o = 128; o > 0; o >>= 1) {
    if (t < o) {
      float v2 = smax[t + o]; int i2 = sidx[t + o];
      if (v2 > smax[t] || (v2 == smax[t] && i2 < sidx[t])) { smax[t] = v2; sidx[t] = i2; }
    }
    __syncthreads();
  }
  float M = smax[0];
  if (t == 0) pred[b] = sidx[0];
  float sum = 0.f;
  for (int c = t; c < CC; c += 256) sum += expf(logits[b * CC + c] - M);
  ssum[t] = sum;
  __syncthreads();
  for (int o = 128; o > 0; o >>= 1) {
    if (t < o) ssum[t] += ssum[t + o];
    __syncthreads();
  }
  float S = ssum[0];
  for (int c = t; c < CC; c += 256) p[b * CC + c] = expf(logits[b * CC + c] - M) / S;
}

// ---------------------------------------------------------------- G = p @ W_fc  [64,768]
__global__ __launch_bounds__(256) void G_kernel(const float* __restrict__ p,
                                                const float* __restrict__ W_fc,
                                                float* __restrict__ G) {
  int b = blockIdx.x;
  int d = blockIdx.y * 256 + threadIdx.x;   // gridDim.y = 3
  __shared__ float ps[CC];
  for (int c = threadIdx.x; c < CC; c += 256) ps[c] = p[b * CC + c];
  __syncthreads();
  float acc = 0.f;
  #pragma unroll 4
  for (int c = 0; c < CC; ++c) acc += ps[c] * W_fc[(size_t)c * DD + d];
  G[b * DD + d] = acc;
}

// ---------------------------------------------------------------- s[b,j] = EPS * ||z|| / ||g||
__global__ __launch_bounds__(256) void s_kernel(const float* __restrict__ emb,
                                                const float* __restrict__ G,
                                                const float* __restrict__ anchors,
                                                const float* __restrict__ W_fc,
                                                float* __restrict__ s) {
  int bid = blockIdx.x;            // 64 * 250 blocks
  int b = bid / 250, jg = bid % 250;
  int wave = threadIdx.x >> 6, lane = threadIdx.x & 63;
  int j = jg * 4 + wave;           // < 1000
  const float* eb = emb + b * DD;
  const float* gb = G + b * DD;
  const float* ar = anchors + (size_t)j * DD;
  const float* wr = W_fc + (size_t)j * DD;
  float zn = 0.f, gn = 0.f;
  for (int k = lane; k < DD; k += 64) {
    float z = ar[k] - eb[k];
    float g = gb[k] - wr[k];
    zn += z * z; gn += g * g;
  }
  #pragma unroll
  for (int o = 1; o < 64; o <<= 1) { zn += __shfl_xor(zn, o); gn += __shfl_xor(gn, o); }
  if (lane == 0) s[b * CC + j] = (EPSA * sqrtf(zn)) / sqrtf(gn);
}

// ---------------------------------------------------------------- main: logits_mix argmax
// M = (b,j) rows, N = c cols, K = 768. 64x64 tile, 4x4 per thread, KT=16.
// A (mix) generated on the fly; argmax fused via packed atomicMax.
#define KT 16
#define PAD 68

__global__ __launch_bounds__(256) void mix_gemm_kernel(const float* __restrict__ emb,
                                                       const float* __restrict__ G,
                                                       const float* __restrict__ anchors,
                                                       const float* __restrict__ W_fc,
                                                       const float* __restrict__ b_fc,
                                                       const float* __restrict__ s,
                                                       unsigned long long* __restrict__ amax) {
  const int jt = blockIdx.x;      // 16 j-tiles (j up to 1023, guarded)
  const int b  = blockIdx.y;      // 64
  const int ct = blockIdx.z;      // 16 c-tiles (c up to 1023, guarded)
  const int j0 = jt * 64, c0 = ct * 64;
  const int tid = threadIdx.x;
  const int tx = tid & 15, ty = tid >> 4;

  __shared__ float sA[KT][PAD];
  __shared__ float sB[KT][PAD];
  __shared__ float es[DD];
  __shared__ float gs[DD];

  const float* embb = emb + b * DD;
  const float* Gb   = G + b * DD;
  for (int k = tid; k < DD; k += 256) { es[k] = embb[k]; gs[k] = Gb[k]; }

  const int lj = tid >> 2;                 // 0..63 staging row
  const int lk = (tid & 3) << 2;           // 0,4,8,12
  const int jl = min(j0 + lj, CC - 1);
  const int cl = min(c0 + lj, CC - 1);
  const float sv = s[b * CC + jl];
  const float* aRow  = anchors + (size_t)jl * DD;
  const float* wjRow = W_fc + (size_t)jl * DD;
  const float* wcRow = W_fc + (size_t)cl * DD;

  float acc[4][4] = {};
  __syncthreads();   // es/gs ready

  for (int k0 = 0; k0 < DD; k0 += KT) {
    float4 an = *(const float4*)(aRow + k0 + lk);
    float4 wj = *(const float4*)(wjRow + k0 + lk);
    float4 wc = *(const float4*)(wcRow + k0 + lk);
    float anv[4] = {an.x, an.y, an.z, an.w};
    float wjv[4] = {wj.x, wj.y, wj.z, wj.w};
    float wcv[4] = {wc.x, wc.y, wc.z, wc.w};
    #pragma unroll
    for (int u = 0; u < 4; ++u) {
      float e = es[k0 + lk + u];
      float g = gs[k0 + lk + u];
      float z = anv[u] - e;
      float alpha = (sv * (g - wjv[u])) / (z + 1e-8f);   // ((EPS*zn/gn)*grads)/(z+1e-8)
      sA[lk + u][lj] = (1.0f - alpha) * e + alpha * anv[u];  // reference mix form
      sB[lk + u][lj] = wcv[u];
    }
    __syncthreads();
    #pragma unroll
    for (int k = 0; k < KT; ++k) {
      float av[4], bv[4];
      #pragma unroll
      for (int i = 0; i < 4; ++i) av[i] = sA[k][ty * 4 + i];
      #pragma unroll
      for (int l = 0; l < 4; ++l) bv[l] = sB[k][tx * 4 + l];
      #pragma unroll
      for (int i = 0; i < 4; ++i)
        #pragma unroll
        for (int l = 0; l < 4; ++l)
          acc[i][l] += av[i] * bv[l];
    }
    __syncthreads();
  }

  // epilogue: +bias, mask invalid c, per-row argmax over this 64-c tile
  #pragma unroll
  for (int i = 0; i < 4; ++i) {
    int j = j0 + ty * 4 + i;
    float best = -3.402823466e38f; int bi = 0;
    #pragma unroll
    for (int l = 0; l < 4; ++l) {
      int c = c0 + tx * 4 + l;
      if (c < CC) {
        float v = acc[i][l] + b_fc[c];
        if (v > best) { best = v; bi = c; }   // c strictly increasing -> first-idx tie ok
      }
    }
    #pragma unroll
    for (int o = 1; o < 16; o <<= 1) {
      float ov = __shfl_xor(best, o);
      int   oi = __shfl_xor(bi, o);
      if (ov > best || (ov == best && oi < bi)) { best = ov; bi = oi; }
    }
    if (tx == 0 && j < CC) {
      unsigned ub = __float_as_uint(best);
      ub = (ub & 0x80000000u) ? ~ub : (ub | 0x80000000u);   // order-preserving map
      unsigned long long key = ((unsigned long long)ub << 32) |
                               (unsigned long long)(0xFFFFFFFFu - (unsigned)bi); // tie -> smaller c
      atomicMax(amax + (size_t)b * CC + j, key);
    }
  }
}

// ---------------------------------------------------------------- counts + all(counts < 3)
__global__ __launch_bounds__(256) void counts_kernel(const unsigned long long* __restrict__ amax,
                                                     const int* __restrict__ pred,
                                                     float* __restrict__ out) {
  int b = blockIdx.x, t = threadIdx.x;
  __shared__ int cnt[CC];
  __shared__ int bad;
  for (int c = t; c < CC; c += 256) cnt[c] = 0;
  if (t == 0) bad = 0;
  __syncthreads();
  if (t == 0) atomicAdd(&cnt[pred[b]], 1);
  for (int j = t; j < CC; j += 256) {
    unsigned low = (unsigned)(amax[(size_t)b * CC + j] & 0xFFFFFFFFull);
    int c = (int)(0xFFFFFFFFu - low);
    atomicAdd(&cnt[c], 1);
  }
  __syncthreads();
  for (int c = t; c < CC; c += 256) if (cnt[c] >= NSIM) bad = 1;
  __syncthreads();
  if (t == 0) out[b] = bad ? 0.0f : 1.0f;
}

// ---------------------------------------------------------------- launch
extern "C" void kernel_launch(void* const* d_in, const int* in_sizes, int n_in,
                              void* d_out, int out_size, void* d_ws, size_t ws_size,
                              hipStream_t stream) {
  const float* x       = (const float*)d_in[0];
  const float* W_emb   = (const float*)d_in[1];
  const float* b_emb   = (const float*)d_in[2];
  const float* W_fc    = (const float*)d_in[3];
  const float* b_fc    = (const float*)d_in[4];
  const float* anchors = (const float*)d_in[5];
  float* out = (float*)d_out;

  // workspace carve (f32 unless noted); total ~1.67 MB
  float* emb    = (float*)d_ws;            // 64*768
  float* logits = emb + BB * DD;           // 64*1000
  float* p      = logits + BB * CC;        // 64*1000
  float* G      = p + BB * CC;             // 64*768
  float* s      = G + BB * DD;             // 64*1000
  int*   pred   = (int*)(s + BB * CC);     // 64
  unsigned long long* amax = (unsigned long long*)(pred + 64);  // 64*1000 u64 (8B aligned)

  hipLaunchKernelGGL(zero_amax_kernel, dim3(250), dim3(256), 0, stream, amax);
  hipLaunchKernelGGL(emb_kernel,    dim3(BB, 3), dim3(256), 0, stream, x, W_emb, b_emb, emb);
  hipLaunchKernelGGL(logits_kernel, dim3(BB, 4), dim3(256), 0, stream, emb, W_fc, b_fc, logits);
  hipLaunchKernelGGL(softmax_kernel, dim3(BB),   dim3(256), 0, stream, logits, p, pred);
  hipLaunchKernelGGL(G_kernel,      dim3(BB, 3), dim3(256), 0, stream, p, W_fc, G);
  hipLaunchKernelGGL(s_kernel,      dim3(BB * 250), dim3(256), 0, stream, emb, G, anchors, W_fc, s);
  hipLaunchKernelGGL(mix_gemm_kernel, dim3(16, BB, 16), dim3(256), 0, stream,
                     emb, G, anchors, W_fc, b_fc, s, amax);
  hipLaunchKernelGGL(counts_kernel, dim3(BB), dim3(256), 0, stream, amax, pred, out);
}

// Round 3
// 524.984 us; speedup vs baseline: 3.2755x; 3.2755x over previous
//
#include <hip/hip_runtime.h>
#include <stdint.h>
#include <stddef.h>

#define BB 64
#define DIN 1024
#define DD 768
#define CC 1000
#define EPSA 0.1f
#define NSIM 3

typedef short  s16x8 __attribute__((ext_vector_type(8)));
typedef float  f32x4 __attribute__((ext_vector_type(4)));

static __device__ __forceinline__ unsigned short f2bf_rne(float x) {
  unsigned u = __float_as_uint(x);
  return (unsigned short)((u + 0x7FFFu + ((u >> 16) & 1u)) >> 16);
}
static __device__ __forceinline__ float bf2f(unsigned short h) {
  return __uint_as_float(((unsigned)h) << 16);
}

// ---------------------------------------------------------------- zero amax
__global__ __launch_bounds__(256) void zero_amax_kernel(unsigned long long* __restrict__ amax) {
  int i = blockIdx.x * 256 + threadIdx.x;
  if (i < BB * CC) amax[i] = 0ull;
}

// ---------------------------------------------------------------- split W_fc -> bf16 hi/lo packed in MFMA B-frag order
// Bp[nt][ks][lane][reg]: c = nt*16 + (lane&15), k = ks*32 + (lane>>4)*8 + reg
__global__ __launch_bounds__(256) void split_W_kernel(const float* __restrict__ W_fc,
                                                      short* __restrict__ Bp_hi,
                                                      short* __restrict__ Bp_lo) {
  int gid = blockIdx.x * 256 + threadIdx.x;     // 64*24*64 = 98304 total
  if (gid >= 64 * 24 * 64) return;
  int lane = gid & 63;
  int ks   = (gid >> 6) % 24;
  int nt   = gid / (64 * 24);
  int c  = nt * 16 + (lane & 15);
  int k0 = ks * 32 + (lane >> 4) * 8;
  s16x8 vh, vl;
  #pragma unroll
  for (int r = 0; r < 8; ++r) {
    float w = (c < CC) ? W_fc[(size_t)c * DD + k0 + r] : 0.0f;
    unsigned short h = f2bf_rne(w);
    vh[r] = (short)h;
    vl[r] = (short)f2bf_rne(w - bf2f(h));
  }
  ((s16x8*)Bp_hi)[gid] = vh;
  ((s16x8*)Bp_lo)[gid] = vl;
}

// ---------------------------------------------------------------- emb = x @ W_emb^T + b_emb   [64,768]
__global__ __launch_bounds__(256) void emb_kernel(const float* __restrict__ x,
                                                  const float* __restrict__ W_emb,
                                                  const float* __restrict__ b_emb,
                                                  float* __restrict__ emb) {
  int b = blockIdx.x;
  int d = blockIdx.y * 256 + threadIdx.x;
  __shared__ float xs[DIN];
  for (int k = threadIdx.x; k < DIN; k += 256) xs[k] = x[b * DIN + k];
  __syncthreads();
  const float4* wr = (const float4*)(W_emb + (size_t)d * DIN);
  float acc = 0.f;
  #pragma unroll 4
  for (int k4 = 0; k4 < DIN / 4; ++k4) {
    float4 w = wr[k4];
    acc += xs[4*k4+0]*w.x + xs[4*k4+1]*w.y + xs[4*k4+2]*w.z + xs[4*k4+3]*w.w;
  }
  emb[b * DD + d] = acc + b_emb[d];
}

// ---------------------------------------------------------------- logits = emb @ W_fc^T + b_fc  [64,1000]
__global__ __launch_bounds__(256) void logits_kernel(const float* __restrict__ emb,
                                                     const float* __restrict__ W_fc,
                                                     const float* __restrict__ b_fc,
                                                     float* __restrict__ logits) {
  int b = blockIdx.x;
  int c = blockIdx.y * 256 + threadIdx.x;
  __shared__ float es[DD];
  for (int k = threadIdx.x; k < DD; k += 256) es[k] = emb[b * DD + k];
  __syncthreads();
  if (c >= CC) return;
  const float4* wr = (const float4*)(W_fc + (size_t)c * DD);
  float acc = 0.f;
  #pragma unroll 4
  for (int k4 = 0; k4 < DD / 4; ++k4) {
    float4 w = wr[k4];
    acc += es[4*k4+0]*w.x + es[4*k4+1]*w.y + es[4*k4+2]*w.z + es[4*k4+3]*w.w;
  }
  logits[b * CC + c] = acc + b_fc[c];
}

// ---------------------------------------------------------------- softmax + argmax(logits)
__global__ __launch_bounds__(256) void softmax_kernel(const float* __restrict__ logits,
                                                      float* __restrict__ p,
                                                      int* __restrict__ pred) {
  int b = blockIdx.x, t = threadIdx.x;
  __shared__ float smax[256];
  __shared__ int   sidx[256];
  __shared__ float ssum[256];
  float m = -3.402823466e38f; int mi = 0;
  for (int c = t; c < CC; c += 256) {
    float v = logits[b * CC + c];
    if (v > m) { m = v; mi = c; }
  }
  smax[t] = m; sidx[t] = mi;
  __syncthreads();
  for (int o = 128; o > 0; o >>= 1) {
    if (t < o) {
      float v2 = smax[t + o]; int i2 = sidx[t + o];
      if (v2 > smax[t] || (v2 == smax[t] && i2 < sidx[t])) { smax[t] = v2; sidx[t] = i2; }
    }
    __syncthreads();
  }
  float M = smax[0];
  if (t == 0) pred[b] = sidx[0];
  float sum = 0.f;
  for (int c = t; c < CC; c += 256) sum += expf(logits[b * CC + c] - M);
  ssum[t] = sum;
  __syncthreads();
  for (int o = 128; o > 0; o >>= 1) {
    if (t < o) ssum[t] += ssum[t + o];
    __syncthreads();
  }
  float S = ssum[0];
  for (int c = t; c < CC; c += 256) p[b * CC + c] = expf(logits[b * CC + c] - M) / S;
}

// ---------------------------------------------------------------- G = p @ W_fc  [64,768]
__global__ __launch_bounds__(256) void G_kernel(const float* __restrict__ p,
                                                const float* __restrict__ W_fc,
                                                float* __restrict__ G) {
  int b = blockIdx.x;
  int d = blockIdx.y * 256 + threadIdx.x;
  __shared__ float ps[CC];
  for (int c = threadIdx.x; c < CC; c += 256) ps[c] = p[b * CC + c];
  __syncthreads();
  float acc = 0.f;
  #pragma unroll 4
  for (int c = 0; c < CC; ++c) acc += ps[c] * W_fc[(size_t)c * DD + d];
  G[b * DD + d] = acc;
}

// ---------------------------------------------------------------- s[b,j] = EPS * ||z|| / ||g||
__global__ __launch_bounds__(256) void s_kernel(const float* __restrict__ emb,
                                                const float* __restrict__ G,
                                                const float* __restrict__ anchors,
                                                const float* __restrict__ W_fc,
                                                float* __restrict__ s) {
  int bid = blockIdx.x;
  int b = bid / 250, jg = bid % 250;
  int wave = threadIdx.x >> 6, lane = threadIdx.x & 63;
  int j = jg * 4 + wave;
  const float* eb = emb + b * DD;
  const float* gb = G + b * DD;
  const float* ar = anchors + (size_t)j * DD;
  const float* wr = W_fc + (size_t)j * DD;
  float zn = 0.f, gn = 0.f;
  for (int k = lane; k < DD; k += 64) {
    float z = ar[k] - eb[k];
    float g = gb[k] - wr[k];
    zn += z * z; gn += g * g;
  }
  #pragma unroll
  for (int o = 1; o < 64; o <<= 1) { zn += __shfl_xor(zn, o); gn += __shfl_xor(gn, o); }
  if (lane == 0) s[b * CC + j] = (EPSA * sqrtf(zn)) / sqrtf(gn);
}

// ---------------------------------------------------------------- main: bf16x3 MFMA GEMM over mix
// M = 64000 flat (b,j) rows tiled BM=64 (grid.x = 1000), N tiled BN=256 (grid.y = 4), K = 768, BK = 64.
// 4 waves; wave w computes all 64 rows x cols [w*64, w*64+64).
// A (mix hi/lo) regenerated per K-step into LDS in MFMA-frag layout, double-buffered.
// B (W hi/lo) loaded from packed global (L2-resident) straight to registers.
__global__ __launch_bounds__(256, 2) void mix_mfma_kernel(const float* __restrict__ emb,
                                                          const float* __restrict__ G,
                                                          const float* __restrict__ anchors,
                                                          const float* __restrict__ W_fc,
                                                          const float* __restrict__ b_fc,
                                                          const float* __restrict__ s,
                                                          const short* __restrict__ Bp_hi,
                                                          const short* __restrict__ Bp_lo,
                                                          unsigned long long* __restrict__ amax) {
  const int mt = blockIdx.x;          // 1000
  const int ct = blockIdx.y;          // 4
  const int tid = threadIdx.x;
  const int w = tid >> 6, lane = tid & 63;

  // A frag LDS: [buf][it(4)][kt(2)][lane(64)][reg(8)] bf16 bits
  __shared__ __attribute__((aligned(16))) short Ah[2][4][2][64][8];
  __shared__ __attribute__((aligned(16))) short Al[2][4][2][64][8];
  __shared__ float es[2][DD];
  __shared__ float gs[2][DD];

  const int r0 = mt * 64;
  const int bLo = r0 / 1000;
  const int bHi = (r0 + 63) / 1000;
  for (int idx = tid; idx < 2 * DD; idx += 256) {
    int slot = idx / DD, k = idx % DD;
    int bb = slot ? bHi : bLo;
    es[slot][k] = emb[bb * DD + k];
    gs[slot][k] = G[bb * DD + k];
  }

  // per-thread regen assignment: row i, k-quarter q (16 k's per step)
  const int i = tid >> 2;             // 0..63
  const int q = tid & 3;              // 0..3
  const int r = r0 + i;
  const int bb = r / 1000;
  const int jj = r - bb * 1000;
  const int slot = (bb != bLo) ? 1 : 0;
  const float sv = s[r];              // s is laid out [b*1000 + j] == flat r
  const float* aRow  = anchors + (size_t)jj * DD;
  const float* wjRow = W_fc + (size_t)jj * DD;
  const int it = i >> 4;
  const int kt_w = q >> 1;
  const int lane0 = (i & 15) + 32 * (q & 1);

  auto REGEN = [&](int step, int buf) {
    const int k0 = step * 64 + q * 16;
    float mixv[16];
    #pragma unroll
    for (int u0 = 0; u0 < 16; u0 += 4) {
      float4 av = *(const float4*)(aRow + k0 + u0);
      float4 wv = *(const float4*)(wjRow + k0 + u0);
      float4 ev = *(const float4*)(&es[slot][k0 + u0]);
      float4 gv = *(const float4*)(&gs[slot][k0 + u0]);
      float aa[4] = {av.x, av.y, av.z, av.w};
      float ww[4] = {wv.x, wv.y, wv.z, wv.w};
      float ee[4] = {ev.x, ev.y, ev.z, ev.w};
      float gg[4] = {gv.x, gv.y, gv.z, gv.w};
      #pragma unroll
      for (int uu = 0; uu < 4; ++uu) {
        float e = ee[uu], a = aa[uu];
        float z = a - e;
        float alpha = (sv * (gg[uu] - ww[uu])) / (z + 1e-8f);  // ref formula
        mixv[u0 + uu] = (1.0f - alpha) * e + alpha * a;        // ref mix form
      }
    }
    s16x8 vh0, vl0, vh1, vl1;
    #pragma unroll
    for (int u = 0; u < 8; ++u) {
      float m0 = mixv[u], m1 = mixv[u + 8];
      unsigned short h0 = f2bf_rne(m0), h1 = f2bf_rne(m1);
      vh0[u] = (short)h0; vh1[u] = (short)h1;
      vl0[u] = (short)f2bf_rne(m0 - bf2f(h0));
      vl1[u] = (short)f2bf_rne(m1 - bf2f(h1));
    }
    *(s16x8*)&Ah[buf][it][kt_w][lane0][0]      = vh0;
    *(s16x8*)&Ah[buf][it][kt_w][lane0 + 16][0] = vh1;
    *(s16x8*)&Al[buf][it][kt_w][lane0][0]      = vl0;
    *(s16x8*)&Al[buf][it][kt_w][lane0 + 16][0] = vl1;
  };

  f32x4 acc[4][4] = {};

  // bias (masked) for this lane's 4 columns
  const int cbase = ct * 256 + w * 64 + (lane & 15);
  float bfv[4];
  #pragma unroll
  for (int nf = 0; nf < 4; ++nf) {
    int c = cbase + nf * 16;
    bfv[nf] = (c < CC) ? b_fc[c] : -3.0e38f;
  }

  REGEN(0, 0);
  __syncthreads();

  const s16x8* BH = (const s16x8*)Bp_hi;
  const s16x8* BL = (const s16x8*)Bp_lo;
  const int ntg0 = ct * 16 + w * 4;

  for (int step = 0; step < 12; ++step) {
    // B frags for this step (L2-resident, issued early)
    s16x8 Bh[2][4], Bl[2][4];
    #pragma unroll
    for (int kt = 0; kt < 2; ++kt)
      #pragma unroll
      for (int nf = 0; nf < 4; ++nf) {
        int idx = ((ntg0 + nf) * 24 + (step * 2 + kt)) * 64 + lane;
        Bh[kt][nf] = BH[idx];
        Bl[kt][nf] = BL[idx];
      }
    // regenerate next A tile into the other buffer (VALU, overlaps MFMA)
    if (step + 1 < 12) REGEN(step + 1, (step + 1) & 1);

    const int buf = step & 1;
    #pragma unroll
    for (int kt = 0; kt < 2; ++kt) {
      #pragma unroll
      for (int mf = 0; mf < 4; ++mf) {
        s16x8 ah = *(const s16x8*)&Ah[buf][mf][kt][lane][0];
        s16x8 al = *(const s16x8*)&Al[buf][mf][kt][lane][0];
        #pragma unroll
        for (int nf = 0; nf < 4; ++nf) {
          acc[mf][nf] = __builtin_amdgcn_mfma_f32_16x16x32_bf16(ah, Bh[kt][nf], acc[mf][nf], 0, 0, 0);
          acc[mf][nf] = __builtin_amdgcn_mfma_f32_16x16x32_bf16(ah, Bl[kt][nf], acc[mf][nf], 0, 0, 0);
          acc[mf][nf] = __builtin_amdgcn_mfma_f32_16x16x32_bf16(al, Bh[kt][nf], acc[mf][nf], 0, 0, 0);
        }
      }
    }
    __syncthreads();
  }

  // epilogue: per-row argmax over this wave's 64-col slice, merge via packed atomicMax
  const int rowq = (lane >> 4) * 4;   // C/D: row = (lane>>4)*4 + reg, col = lane&15  [m89]
  #pragma unroll
  for (int mf = 0; mf < 4; ++mf) {
    #pragma unroll
    for (int rr = 0; rr < 4; ++rr) {
      float best = -3.402823466e38f; int bi = 0;
      #pragma unroll
      for (int nf = 0; nf < 4; ++nf) {
        float v = acc[mf][nf][rr] + bfv[nf];
        int c = cbase + nf * 16;
        if (v > best) { best = v; bi = c; }
      }
      #pragma unroll
      for (int o = 1; o < 16; o <<= 1) {
        float ov = __shfl_xor(best, o);
        int   oi = __shfl_xor(bi, o);
        if (ov > best || (ov == best && oi < bi)) { best = ov; bi = oi; }
      }
      if ((lane & 15) == 0) {
        int row = r0 + mf * 16 + rowq + rr;
        unsigned ub = __float_as_uint(best);
        ub = (ub & 0x80000000u) ? ~ub : (ub | 0x80000000u);
        unsigned long long key = ((unsigned long long)ub << 32) |
                                 (unsigned long long)(0xFFFFFFFFu - (unsigned)bi);
        atomicMax(amax + row, key);
      }
    }
  }
}

// ---------------------------------------------------------------- counts + all(counts < 3)
__global__ __launch_bounds__(256) void counts_kernel(const unsigned long long* __restrict__ amax,
                                                     const int* __restrict__ pred,
                                                     float* __restrict__ out) {
  int b = blockIdx.x, t = threadIdx.x;
  __shared__ int cnt[CC];
  __shared__ int bad;
  for (int c = t; c < CC; c += 256) cnt[c] = 0;
  if (t == 0) bad = 0;
  __syncthreads();
  if (t == 0) atomicAdd(&cnt[pred[b]], 1);
  for (int j = t; j < CC; j += 256) {
    unsigned low = (unsigned)(amax[(size_t)b * CC + j] & 0xFFFFFFFFull);
    int c = (int)(0xFFFFFFFFu - low);
    atomicAdd(&cnt[c], 1);
  }
  __syncthreads();
  for (int c = t; c < CC; c += 256) if (cnt[c] >= NSIM) bad = 1;
  __syncthreads();
  if (t == 0) out[b] = bad ? 0.0f : 1.0f;
}

// ---------------------------------------------------------------- launch
extern "C" void kernel_launch(void* const* d_in, const int* in_sizes, int n_in,
                              void* d_out, int out_size, void* d_ws, size_t ws_size,
                              hipStream_t stream) {
  const float* x       = (const float*)d_in[0];
  const float* W_emb   = (const float*)d_in[1];
  const float* b_emb   = (const float*)d_in[2];
  const float* W_fc    = (const float*)d_in[3];
  const float* b_fc    = (const float*)d_in[4];
  const float* anchors = (const float*)d_in[5];
  float* out = (float*)d_out;

  // workspace carve (~4.82 MB)
  float* emb    = (float*)d_ws;            // 64*768
  float* logits = emb + BB * DD;           // 64*1000
  float* p      = logits + BB * CC;        // 64*1000
  float* G      = p + BB * CC;             // 64*768
  float* s      = G + BB * DD;             // 64*1000
  int*   pred   = (int*)(s + BB * CC);     // 64 ints
  unsigned long long* amax = (unsigned long long*)(pred + 64);    // 64000 u64
  short* Bp_hi = (short*)(amax + BB * CC); // 64*24*64*8 bf16 bits
  short* Bp_lo = Bp_hi + 64 * 24 * 64 * 8;

  hipLaunchKernelGGL(zero_amax_kernel, dim3(250), dim3(256), 0, stream, amax);
  hipLaunchKernelGGL(split_W_kernel, dim3(384), dim3(256), 0, stream, W_fc, Bp_hi, Bp_lo);
  hipLaunchKernelGGL(emb_kernel,    dim3(BB, 3), dim3(256), 0, stream, x, W_emb, b_emb, emb);
  hipLaunchKernelGGL(logits_kernel, dim3(BB, 4), dim3(256), 0, stream, emb, W_fc, b_fc, logits);
  hipLaunchKernelGGL(softmax_kernel, dim3(BB),   dim3(256), 0, stream, logits, p, pred);
  hipLaunchKernelGGL(G_kernel,      dim3(BB, 3), dim3(256), 0, stream, p, W_fc, G);
  hipLaunchKernelGGL(s_kernel,      dim3(BB * 250), dim3(256), 0, stream, emb, G, anchors, W_fc, s);
  hipLaunchKernelGGL(mix_mfma_kernel, dim3(1000, 4), dim3(256), 0, stream,
                     emb, G, anchors, W_fc, b_fc, s, Bp_hi, Bp_lo, amax);
  hipLaunchKernelGGL(counts_kernel, dim3(BB), dim3(256), 0, stream, amax, pred, out);
}

// Round 5
// 331.092 us; speedup vs baseline: 5.1936x; 1.5856x over previous
//
#include <hip/hip_runtime.h>
#include <stdint.h>
#include <stddef.h>

#define BB 64
#define DIN 1024
#define DD 768
#define CC 1000
#define EPSA 0.1f
#define NSIM 3

typedef short  s16x8 __attribute__((ext_vector_type(8)));
typedef float  f32x4 __attribute__((ext_vector_type(4)));

static __device__ __forceinline__ unsigned short f2bf_rne(float x) {
  unsigned u = __float_as_uint(x);
  return (unsigned short)((u + 0x7FFFu + ((u >> 16) & 1u)) >> 16);
}

// ---------------------------------------------------------------- zero amax
__global__ __launch_bounds__(256) void zero_amax_kernel(unsigned long long* __restrict__ amax) {
  int i = blockIdx.x * 256 + threadIdx.x;
  if (i < BB * CC) amax[i] = 0ull;
}

// ---------------------------------------------------------------- W_fc -> bf16 packed in MFMA B-frag order
// Bp[nt][ks][lane][reg]: c = nt*16 + (lane&15), k = ks*32 + (lane>>4)*8 + reg
__global__ __launch_bounds__(256) void split_W_kernel(const float* __restrict__ W_fc,
                                                      short* __restrict__ Bp) {
  int gid = blockIdx.x * 256 + threadIdx.x;     // 64*24*64 = 98304 total
  if (gid >= 64 * 24 * 64) return;
  int lane = gid & 63;
  int ks   = (gid >> 6) % 24;
  int nt   = gid / (64 * 24);
  int c  = nt * 16 + (lane & 15);
  int k0 = ks * 32 + (lane >> 4) * 8;
  s16x8 vh;
  #pragma unroll
  for (int r = 0; r < 8; ++r) {
    float w = (c < CC) ? W_fc[(size_t)c * DD + k0 + r] : 0.0f;
    vh[r] = (short)f2bf_rne(w);
  }
  ((s16x8*)Bp)[gid] = vh;
}

// ---------------------------------------------------------------- emb = x @ W_emb^T + b_emb   [64,768]
__global__ __launch_bounds__(256) void emb_kernel(const float* __restrict__ x,
                                                  const float* __restrict__ W_emb,
                                                  const float* __restrict__ b_emb,
                                                  float* __restrict__ emb) {
  int b = blockIdx.x;
  int d = blockIdx.y * 256 + threadIdx.x;
  __shared__ float xs[DIN];
  for (int k = threadIdx.x; k < DIN; k += 256) xs[k] = x[b * DIN + k];
  __syncthreads();
  const float4* wr = (const float4*)(W_emb + (size_t)d * DIN);
  float acc = 0.f;
  #pragma unroll 4
  for (int k4 = 0; k4 < DIN / 4; ++k4) {
    float4 w = wr[k4];
    acc += xs[4*k4+0]*w.x + xs[4*k4+1]*w.y + xs[4*k4+2]*w.z + xs[4*k4+3]*w.w;
  }
  emb[b * DD + d] = acc + b_emb[d];
}

// ---------------------------------------------------------------- logits = emb @ W_fc^T + b_fc  [64,1000]
__global__ __launch_bounds__(256) void logits_kernel(const float* __restrict__ emb,
                                                     const float* __restrict__ W_fc,
                                                     const float* __restrict__ b_fc,
                                                     float* __restrict__ logits) {
  int b = blockIdx.x;
  int c = blockIdx.y * 256 + threadIdx.x;
  __shared__ float es[DD];
  for (int k = threadIdx.x; k < DD; k += 256) es[k] = emb[b * DD + k];
  __syncthreads();
  if (c >= CC) return;
  const float4* wr = (const float4*)(W_fc + (size_t)c * DD);
  float acc = 0.f;
  #pragma unroll 4
  for (int k4 = 0; k4 < DD / 4; ++k4) {
    float4 w = wr[k4];
    acc += es[4*k4+0]*w.x + es[4*k4+1]*w.y + es[4*k4+2]*w.z + es[4*k4+3]*w.w;
  }
  logits[b * CC + c] = acc + b_fc[c];
}

// ---------------------------------------------------------------- softmax + argmax(logits)
__global__ __launch_bounds__(256) void softmax_kernel(const float* __restrict__ logits,
                                                      float* __restrict__ p,
                                                      int* __restrict__ pred) {
  int b = blockIdx.x, t = threadIdx.x;
  __shared__ float smax[256];
  __shared__ int   sidx[256];
  __shared__ float ssum[256];
  float m = -3.402823466e38f; int mi = 0;
  for (int c = t; c < CC; c += 256) {
    float v = logits[b * CC + c];
    if (v > m) { m = v; mi = c; }
  }
  smax[t] = m; sidx[t] = mi;
  __syncthreads();
  for (int o = 128; o > 0; o >>= 1) {
    if (t < o) {
      float v2 = smax[t + o]; int i2 = sidx[t + o];
      if (v2 > smax[t] || (v2 == smax[t] && i2 < sidx[t])) { smax[t] = v2; sidx[t] = i2; }
    }
    __syncthreads();
  }
  float M = smax[0];
  if (t == 0) pred[b] = sidx[0];
  float sum = 0.f;
  for (int c = t; c < CC; c += 256) sum += expf(logits[b * CC + c] - M);
  ssum[t] = sum;
  __syncthreads();
  for (int o = 128; o > 0; o >>= 1) {
    if (t < o) ssum[t] += ssum[t + o];
    __syncthreads();
  }
  float S = ssum[0];
  for (int c = t; c < CC; c += 256) p[b * CC + c] = expf(logits[b * CC + c] - M) / S;
}

// ---------------------------------------------------------------- G = p @ W_fc  [64,768]
__global__ __launch_bounds__(256) void G_kernel(const float* __restrict__ p,
                                                const float* __restrict__ W_fc,
                                                float* __restrict__ G) {
  int b = blockIdx.x;
  int d = blockIdx.y * 256 + threadIdx.x;
  __shared__ float ps[CC];
  for (int c = threadIdx.x; c < CC; c += 256) ps[c] = p[b * CC + c];
  __syncthreads();
  float acc = 0.f;
  #pragma unroll 4
  for (int c = 0; c < CC; ++c) acc += ps[c] * W_fc[(size_t)c * DD + d];
  G[b * DD + d] = acc;
}

// ---------------------------------------------------------------- s[b,j] = EPS * ||z|| / ||g||
__global__ __launch_bounds__(256) void s_kernel(const float* __restrict__ emb,
                                                const float* __restrict__ G,
                                                const float* __restrict__ anchors,
                                                const float* __restrict__ W_fc,
                                                float* __restrict__ s) {
  int bid = blockIdx.x;
  int b = bid / 250, jg = bid % 250;
  int wave = threadIdx.x >> 6, lane = threadIdx.x & 63;
  int j = jg * 4 + wave;
  const float* eb = emb + b * DD;
  const float* gb = G + b * DD;
  const float* ar = anchors + (size_t)j * DD;
  const float* wr = W_fc + (size_t)j * DD;
  float zn = 0.f, gn = 0.f;
  for (int k = lane; k < DD; k += 64) {
    float z = ar[k] - eb[k];
    float g = gb[k] - wr[k];
    zn += z * z; gn += g * g;
  }
  #pragma unroll
  for (int o = 1; o < 64; o <<= 1) { zn += __shfl_xor(zn, o); gn += __shfl_xor(gn, o); }
  if (lane == 0) s[b * CC + j] = (EPSA * sqrtf(zn)) / sqrtf(gn);
}

// ---------------------------------------------------------------- main: single-bf16 MFMA GEMM over mix
// M = 64000 rows tiled BM=128 (grid.x = 500), N tiled BN=512 (grid.y = 2), K = 768, BK = 64.
// 512 threads = 8 waves (2 mw x 4 nw); wave computes 64 rows x 128 cols (4 x 8 frags).
// A (mix bf16) regenerated per K-step into LDS in MFMA-frag layout, double-buffered (rcp div).
// B (W bf16) loaded from packed global (L2-resident, 1.57 MB) straight to registers.
__global__ __launch_bounds__(512, 2) void mix_mfma_kernel(const float* __restrict__ emb,
                                                          const float* __restrict__ G,
                                                          const float* __restrict__ anchors,
                                                          const float* __restrict__ W_fc,
                                                          const float* __restrict__ b_fc,
                                                          const float* __restrict__ s,
                                                          const short* __restrict__ Bp,
                                                          unsigned long long* __restrict__ amax) {
  const int mt = blockIdx.x;          // 500
  const int ct = blockIdx.y;          // 2
  const int tid = threadIdx.x;        // 512
  const int w = tid >> 6, lane = tid & 63;
  const int mw = w >> 2, nw = w & 3;

  // A frag LDS: [buf][mfrag(8)][kt(2)][lane(64)][reg(8)] bf16 bits = 32 KB
  __shared__ __attribute__((aligned(16))) short Ah[2][8][2][64][8];
  __shared__ float es[2][DD];
  __shared__ float gs[2][DD];

  const int r0 = mt * 128;
  const int bLo = r0 / 1000;
  const int bHi = (r0 + 127) / 1000;
  for (int idx = tid; idx < 2 * DD; idx += 512) {
    int slot = idx / DD, k = idx % DD;
    int bb = slot ? bHi : bLo;
    es[slot][k] = emb[bb * DD + k];
    gs[slot][k] = G[bb * DD + k];
  }

  // per-thread regen assignment: row i (0..127), k-quarter q (16 k's per step)
  const int i = tid >> 2;
  const int q = tid & 3;
  const int r = r0 + i;
  const int bb = r / 1000;
  const int jj = r - bb * 1000;
  const int slot = (bb != bLo) ? 1 : 0;
  const float sv = s[r];
  const float* aRow  = anchors + (size_t)jj * DD;
  const float* wjRow = W_fc + (size_t)jj * DD;
  const int it = i >> 4;              // mfrag 0..7
  const int kt_w = q >> 1;
  const int lane0 = (i & 15) + 32 * (q & 1);

  auto REGEN = [&](int step, int buf) {
    const int k0 = step * 64 + q * 16;
    float mixv[16];
    #pragma unroll
    for (int u0 = 0; u0 < 16; u0 += 4) {
      float4 av = *(const float4*)(aRow + k0 + u0);
      float4 wv = *(const float4*)(wjRow + k0 + u0);
      float4 ev = *(const float4*)(&es[slot][k0 + u0]);
      float4 gv = *(const float4*)(&gs[slot][k0 + u0]);
      float aa[4] = {av.x, av.y, av.z, av.w};
      float ww[4] = {wv.x, wv.y, wv.z, wv.w};
      float ee[4] = {ev.x, ev.y, ev.z, ev.w};
      float gg[4] = {gv.x, gv.y, gv.z, gv.w};
      #pragma unroll
      for (int uu = 0; uu < 4; ++uu) {
        float e = ee[uu], a = aa[uu];
        float z = a - e;
        float alpha = sv * (gg[uu] - ww[uu]) * __builtin_amdgcn_rcpf(z + 1e-8f);
        mixv[u0 + uu] = (1.0f - alpha) * e + alpha * a;
      }
    }
    s16x8 vh0, vh1;
    #pragma unroll
    for (int u = 0; u < 8; ++u) {
      vh0[u] = (short)f2bf_rne(mixv[u]);
      vh1[u] = (short)f2bf_rne(mixv[u + 8]);
    }
    *(s16x8*)&Ah[buf][it][kt_w][lane0][0]      = vh0;
    *(s16x8*)&Ah[buf][it][kt_w][lane0 + 16][0] = vh1;
  };

  f32x4 acc[4][8] = {};

  // bias (masked) for this lane's 8 columns
  const int cbase = ct * 512 + nw * 128 + (lane & 15);
  float bfv[8];
  #pragma unroll
  for (int nf = 0; nf < 8; ++nf) {
    int c = cbase + nf * 16;
    bfv[nf] = (c < CC) ? b_fc[c] : -3.0e38f;
  }

  REGEN(0, 0);
  __syncthreads();

  const s16x8* BH = (const s16x8*)Bp;
  const int ntg0 = ct * 32 + nw * 8;

  for (int step = 0; step < 12; ++step) {
    // B frags kt=0 issued first (latency hidden under REGEN's VALU)
    s16x8 Bh0[8];
    #pragma unroll
    for (int nf = 0; nf < 8; ++nf)
      Bh0[nf] = BH[((ntg0 + nf) * 24 + step * 2 + 0) * 64 + lane];

    if (step + 1 < 12) REGEN(step + 1, (step + 1) & 1);

    s16x8 Bh1[8];
    #pragma unroll
    for (int nf = 0; nf < 8; ++nf)
      Bh1[nf] = BH[((ntg0 + nf) * 24 + step * 2 + 1) * 64 + lane];

    const int buf = step & 1;
    #pragma unroll
    for (int mf = 0; mf < 4; ++mf) {
      s16x8 ah = *(const s16x8*)&Ah[buf][mw * 4 + mf][0][lane][0];
      #pragma unroll
      for (int nf = 0; nf < 8; ++nf)
        acc[mf][nf] = __builtin_amdgcn_mfma_f32_16x16x32_bf16(ah, Bh0[nf], acc[mf][nf], 0, 0, 0);
    }
    #pragma unroll
    for (int mf = 0; mf < 4; ++mf) {
      s16x8 ah = *(const s16x8*)&Ah[buf][mw * 4 + mf][1][lane][0];
      #pragma unroll
      for (int nf = 0; nf < 8; ++nf)
        acc[mf][nf] = __builtin_amdgcn_mfma_f32_16x16x32_bf16(ah, Bh1[nf], acc[mf][nf], 0, 0, 0);
    }
    __syncthreads();
  }

  // epilogue: per-row argmax over this wave's 128-col slice, merge via packed atomicMax
  const int rowq = (lane >> 4) * 4;   // C/D: row = (lane>>4)*4 + reg, col = lane&15  [m89]
  #pragma unroll
  for (int mf = 0; mf < 4; ++mf) {
    #pragma unroll
    for (int rr = 0; rr < 4; ++rr) {
      float best = -3.402823466e38f; int bi = 0;
      #pragma unroll
      for (int nf = 0; nf < 8; ++nf) {
        float v = acc[mf][nf][rr] + bfv[nf];
        int c = cbase + nf * 16;
        if (v > best) { best = v; bi = c; }
      }
      #pragma unroll
      for (int o = 1; o < 16; o <<= 1) {
        float ov = __shfl_xor(best, o);
        int   oi = __shfl_xor(bi, o);
        if (ov > best || (ov == best && oi < bi)) { best = ov; bi = oi; }
      }
      if ((lane & 15) == 0) {
        int row = r0 + (mw * 4 + mf) * 16 + rowq + rr;
        unsigned ub = __float_as_uint(best);
        ub = (ub & 0x80000000u) ? ~ub : (ub | 0x80000000u);
        unsigned long long key = ((unsigned long long)ub << 32) |
                                 (unsigned long long)(0xFFFFFFFFu - (unsigned)bi);
        atomicMax(amax + row, key);
      }
    }
  }
}

// ---------------------------------------------------------------- counts + all(counts < 3)
__global__ __launch_bounds__(256) void counts_kernel(const unsigned long long* __restrict__ amax,
                                                     const int* __restrict__ pred,
                                                     float* __restrict__ out) {
  int b = blockIdx.x, t = threadIdx.x;
  __shared__ int cnt[CC];
  __shared__ int bad;
  for (int c = t; c < CC; c += 256) cnt[c] = 0;
  if (t == 0) bad = 0;
  __syncthreads();
  if (t == 0) atomicAdd(&cnt[pred[b]], 1);
  for (int j = t; j < CC; j += 256) {
    unsigned low = (unsigned)(amax[(size_t)b * CC + j] & 0xFFFFFFFFull);
    int c = (int)(0xFFFFFFFFu - low);
    atomicAdd(&cnt[c], 1);
  }
  __syncthreads();
  for (int c = t; c < CC; c += 256) if (cnt[c] >= NSIM) bad = 1;
  __syncthreads();
  if (t == 0) out[b] = bad ? 0.0f : 1.0f;
}

// ---------------------------------------------------------------- launch
extern "C" void kernel_launch(void* const* d_in, const int* in_sizes, int n_in,
                              void* d_out, int out_size, void* d_ws, size_t ws_size,
                              hipStream_t stream) {
  const float* x       = (const float*)d_in[0];
  const float* W_emb   = (const float*)d_in[1];
  const float* b_emb   = (const float*)d_in[2];
  const float* W_fc    = (const float*)d_in[3];
  const float* b_fc    = (const float*)d_in[4];
  const float* anchors = (const float*)d_in[5];
  float* out = (float*)d_out;

  // workspace carve (~3.3 MB)
  float* emb    = (float*)d_ws;            // 64*768
  float* logits = emb + BB * DD;           // 64*1000
  float* p      = logits + BB * CC;        // 64*1000
  float* G      = p + BB * CC;             // 64*768
  float* s      = G + BB * DD;             // 64*1000
  int*   pred   = (int*)(s + BB * CC);     // 64 ints
  unsigned long long* amax = (unsigned long long*)(pred + 64);    // 64000 u64
  short* Bp = (short*)(amax + BB * CC);    // 64*24*64*8 bf16 bits (1.57 MB)

  hipLaunchKernelGGL(zero_amax_kernel, dim3(250), dim3(256), 0, stream, amax);
  hipLaunchKernelGGL(split_W_kernel, dim3(384), dim3(256), 0, stream, W_fc, Bp);
  hipLaunchKernelGGL(emb_kernel,    dim3(BB, 3), dim3(256), 0, stream, x, W_emb, b_emb, emb);
  hipLaunchKernelGGL(logits_kernel, dim3(BB, 4), dim3(256), 0, stream, emb, W_fc, b_fc, logits);
  hipLaunchKernelGGL(softmax_kernel, dim3(BB),   dim3(256), 0, stream, logits, p, pred);
  hipLaunchKernelGGL(G_kernel,      dim3(BB, 3), dim3(256), 0, stream, p, W_fc, G);
  hipLaunchKernelGGL(s_kernel,      dim3(BB * 250), dim3(256), 0, stream, emb, G, anchors, W_fc, s);
  hipLaunchKernelGGL(mix_mfma_kernel, dim3(500, 2), dim3(512), 0, stream,
                     emb, G, anchors, W_fc, b_fc, s, Bp, amax);
  hipLaunchKernelGGL(counts_kernel, dim3(BB), dim3(256), 0, stream, amax, pred, out);
}

// Round 6
// 268.782 us; speedup vs baseline: 6.3977x; 1.2318x over previous
//
#include <hip/hip_runtime.h>
#include <stdint.h>
#include <stddef.h>

#define BB 64
#define DIN 1024
#define DD 768
#define CC 1000
#define EPSA 0.1f
#define NSIM 3

typedef short  s16x8 __attribute__((ext_vector_type(8)));
typedef float  f32x4 __attribute__((ext_vector_type(4)));

static __device__ __forceinline__ unsigned short f2bf_rne(float x) {
  unsigned u = __float_as_uint(x);
  return (unsigned short)((u + 0x7FFFu + ((u >> 16) & 1u)) >> 16);
}

// ---------------------------------------------------------------- W_fc -> bf16 packed in MFMA frag order
// Bp[nt][ks][lane][reg]: row = nt*16 + (lane&15), k = ks*32 + (lane>>4)*8 + reg
// Serves BOTH operands of V = W @ W^T (A: row=lane&15; B: col=lane&15 — same mapping).
__global__ __launch_bounds__(256) void pack_W_kernel(const float* __restrict__ W_fc,
                                                     short* __restrict__ Bp) {
  int gid = blockIdx.x * 256 + threadIdx.x;     // 64*24*64 = 98304
  if (gid >= 64 * 24 * 64) return;
  int lane = gid & 63;
  int ks   = (gid >> 6) % 24;
  int nt   = gid / (64 * 24);
  int c  = nt * 16 + (lane & 15);
  int k0 = ks * 32 + (lane >> 4) * 8;
  s16x8 vh;
  #pragma unroll
  for (int r = 0; r < 8; ++r) {
    float w = (c < CC) ? W_fc[(size_t)c * DD + k0 + r] : 0.0f;
    vh[r] = (short)f2bf_rne(w);
  }
  ((s16x8*)Bp)[gid] = vh;
}

// ---------------------------------------------------------------- V = W_fc @ W_fc^T  [1024,1024] (bf16 MFMA)
__global__ __launch_bounds__(256) void V_kernel(const short* __restrict__ Bp,
                                                float* __restrict__ V) {
  const int tid = threadIdx.x;
  const int w = tid >> 6, lane = tid & 63;
  const int rnt = blockIdx.x * 4 + w;       // 0..63: rows rnt*16..+15
  const int cb  = blockIdx.y;               // 0..15: cols cb*64..+63
  const s16x8* BH = (const s16x8*)Bp;
  f32x4 acc[4] = {};
  for (int ks = 0; ks < 24; ++ks) {
    s16x8 a = BH[(rnt * 24 + ks) * 64 + lane];
    #pragma unroll
    for (int nf = 0; nf < 4; ++nf) {
      s16x8 bf = BH[((cb * 4 + nf) * 24 + ks) * 64 + lane];
      acc[nf] = __builtin_amdgcn_mfma_f32_16x16x32_bf16(a, bf, acc[nf], 0, 0, 0);
    }
  }
  const int r0 = rnt * 16 + (lane >> 4) * 4;   // C/D: row=(lane>>4)*4+reg, col=lane&15 [m89]
  const int c0 = cb * 64 + (lane & 15);
  #pragma unroll
  for (int nf = 0; nf < 4; ++nf)
    #pragma unroll
    for (int rr = 0; rr < 4; ++rr)
      V[(size_t)(r0 + rr) * 1024 + c0 + nf * 16] = acc[nf][rr];
}

// ---------------------------------------------------------------- An2[j] = ||anchors_j||^2, Vd[j] = ||W_fc_j||^2 (fp32)
__global__ __launch_bounds__(256) void norms_jc_kernel(const float* __restrict__ anchors,
                                                       const float* __restrict__ W_fc,
                                                       float* __restrict__ An2,
                                                       float* __restrict__ Vd) {
  int w = threadIdx.x >> 6, lane = threadIdx.x & 63;
  int j = blockIdx.x * 4 + w;               // grid 250 -> j < 1000
  float an = 0.f, vd = 0.f;
  for (int k = lane; k < DD; k += 64) {
    float a = anchors[(size_t)j * DD + k]; an += a * a;
    float ww = W_fc[(size_t)j * DD + k];   vd += ww * ww;
  }
  #pragma unroll
  for (int o = 1; o < 64; o <<= 1) { an += __shfl_xor(an, o); vd += __shfl_xor(vd, o); }
  if (lane == 0) { An2[j] = an; Vd[j] = vd; }
}

// ---------------------------------------------------------------- emb = x @ W_emb^T + b_emb   [64,768]
__global__ __launch_bounds__(256) void emb_kernel(const float* __restrict__ x,
                                                  const float* __restrict__ W_emb,
                                                  const float* __restrict__ b_emb,
                                                  float* __restrict__ emb) {
  int b = blockIdx.x;
  int d = blockIdx.y * 256 + threadIdx.x;
  __shared__ float xs[DIN];
  for (int k = threadIdx.x; k < DIN; k += 256) xs[k] = x[b * DIN + k];
  __syncthreads();
  const float4* wr = (const float4*)(W_emb + (size_t)d * DIN);
  float acc = 0.f;
  #pragma unroll 4
  for (int k4 = 0; k4 < DIN / 4; ++k4) {
    float4 w = wr[k4];
    acc += xs[4*k4+0]*w.x + xs[4*k4+1]*w.y + xs[4*k4+2]*w.z + xs[4*k4+3]*w.w;
  }
  emb[b * DD + d] = acc + b_emb[d];
}

// ---------------------------------------------------------------- logits = emb @ W_fc^T + b_fc  [64,1000]
__global__ __launch_bounds__(256) void logits_kernel(const float* __restrict__ emb,
                                                     const float* __restrict__ W_fc,
                                                     const float* __restrict__ b_fc,
                                                     float* __restrict__ logits) {
  int b = blockIdx.x;
  int c = blockIdx.y * 256 + threadIdx.x;
  __shared__ float es[DD];
  for (int k = threadIdx.x; k < DD; k += 256) es[k] = emb[b * DD + k];
  __syncthreads();
  if (c >= CC) return;
  const float4* wr = (const float4*)(W_fc + (size_t)c * DD);
  float acc = 0.f;
  #pragma unroll 4
  for (int k4 = 0; k4 < DD / 4; ++k4) {
    float4 w = wr[k4];
    acc += es[4*k4+0]*w.x + es[4*k4+1]*w.y + es[4*k4+2]*w.z + es[4*k4+3]*w.w;
  }
  logits[b * CC + c] = acc + b_fc[c];
}

// ---------------------------------------------------------------- AE[b,j] = emb_b . anchors_j  [64,1000]
__global__ __launch_bounds__(256) void AE_kernel(const float* __restrict__ emb,
                                                 const float* __restrict__ anchors,
                                                 float* __restrict__ AE) {
  int b = blockIdx.x;
  int j = blockIdx.y * 256 + threadIdx.x;
  __shared__ float es[DD];
  for (int k = threadIdx.x; k < DD; k += 256) es[k] = emb[b * DD + k];
  __syncthreads();
  if (j >= CC) return;
  const float4* ar = (const float4*)(anchors + (size_t)j * DD);
  float acc = 0.f;
  #pragma unroll 4
  for (int k4 = 0; k4 < DD / 4; ++k4) {
    float4 a = ar[k4];
    acc += es[4*k4+0]*a.x + es[4*k4+1]*a.y + es[4*k4+2]*a.z + es[4*k4+3]*a.w;
  }
  AE[b * CC + j] = acc;
}

// ---------------------------------------------------------------- softmax + argmax(logits)
__global__ __launch_bounds__(256) void softmax_kernel(const float* __restrict__ logits,
                                                      float* __restrict__ p,
                                                      int* __restrict__ pred) {
  int b = blockIdx.x, t = threadIdx.x;
  __shared__ float smax[256];
  __shared__ int   sidx[256];
  __shared__ float ssum[256];
  float m = -3.402823466e38f; int mi = 0;
  for (int c = t; c < CC; c += 256) {
    float v = logits[b * CC + c];
    if (v > m) { m = v; mi = c; }
  }
  smax[t] = m; sidx[t] = mi;
  __syncthreads();
  for (int o = 128; o > 0; o >>= 1) {
    if (t < o) {
      float v2 = smax[t + o]; int i2 = sidx[t + o];
      if (v2 > smax[t] || (v2 == smax[t] && i2 < sidx[t])) { smax[t] = v2; sidx[t] = i2; }
    }
    __syncthreads();
  }
  float M = smax[0];
  if (t == 0) pred[b] = sidx[0];
  float sum = 0.f;
  for (int c = t; c < CC; c += 256) sum += expf(logits[b * CC + c] - M);
  ssum[t] = sum;
  __syncthreads();
  for (int o = 128; o > 0; o >>= 1) {
    if (t < o) ssum[t] += ssum[t + o];
    __syncthreads();
  }
  float S = ssum[0];
  for (int c = t; c < CC; c += 256) p[b * CC + c] = expf(logits[b * CC + c] - M) / S;
}

// ---------------------------------------------------------------- G = p @ W_fc  [64,768]
__global__ __launch_bounds__(256) void G_kernel(const float* __restrict__ p,
                                                const float* __restrict__ W_fc,
                                                float* __restrict__ G) {
  int b = blockIdx.x;
  int d = blockIdx.y * 256 + threadIdx.x;
  __shared__ float ps[CC];
  for (int c = threadIdx.x; c < CC; c += 256) ps[c] = p[b * CC + c];
  __syncthreads();
  float acc = 0.f;
  #pragma unroll 4
  for (int c = 0; c < CC; ++c) acc += ps[c] * W_fc[(size_t)c * DD + d];
  G[b * DD + d] = acc;
}

// ---------------------------------------------------------------- u[b,c] = G_b . W_fc_c  [64,1000] (fp32)
__global__ __launch_bounds__(256) void u_kernel(const float* __restrict__ G,
                                                const float* __restrict__ W_fc,
                                                float* __restrict__ u) {
  int b = blockIdx.x;
  int c = blockIdx.y * 256 + threadIdx.x;
  __shared__ float gsh[DD];
  for (int k = threadIdx.x; k < DD; k += 256) gsh[k] = G[b * DD + k];
  __syncthreads();
  if (c >= CC) return;
  const float4* wr = (const float4*)(W_fc + (size_t)c * DD);
  float acc = 0.f;
  #pragma unroll 4
  for (int k4 = 0; k4 < DD / 4; ++k4) {
    float4 w = wr[k4];
    acc += gsh[4*k4+0]*w.x + gsh[4*k4+1]*w.y + gsh[4*k4+2]*w.z + gsh[4*k4+3]*w.w;
  }
  u[b * CC + c] = acc;
}

// ---------------------------------------------------------------- En2[b] = ||emb_b||^2, Gn2[b] = ||G_b||^2
__global__ __launch_bounds__(256) void normsB_kernel(const float* __restrict__ emb,
                                                     const float* __restrict__ G,
                                                     float* __restrict__ En2,
                                                     float* __restrict__ Gn2) {
  int b = blockIdx.x, t = threadIdx.x;
  float e = 0.f, g = 0.f;
  for (int k = t; k < DD; k += 256) {
    float x1 = emb[b * DD + k]; e += x1 * x1;
    float x2 = G[b * DD + k];   g += x2 * x2;
  }
  #pragma unroll
  for (int o = 1; o < 64; o <<= 1) { e += __shfl_xor(e, o); g += __shfl_xor(g, o); }
  __shared__ float se[4], sg[4];
  int w = t >> 6, lane = t & 63;
  if (lane == 0) { se[w] = e; sg[w] = g; }
  __syncthreads();
  if (t == 0) { En2[b] = se[0]+se[1]+se[2]+se[3]; Gn2[b] = sg[0]+sg[1]+sg[2]+sg[3]; }
}

// ---------------------------------------------------------------- scan: per (b,j) argmax_c of
// logits[b,c] + s[b,j]*(u[b,c] - V[j,c]),  s from norm algebra. Writes pm[b,j].
__global__ __launch_bounds__(256) void scan_kernel(const float* __restrict__ logits,
                                                   const float* __restrict__ u,
                                                   const float* __restrict__ AE,
                                                   const float* __restrict__ An2,
                                                   const float* __restrict__ Vd,
                                                   const float* __restrict__ En2,
                                                   const float* __restrict__ Gn2,
                                                   const float* __restrict__ V,
                                                   int* __restrict__ pm) {
  const int b = blockIdx.x, jb = blockIdx.y;
  const int tid = threadIdx.x, w = tid >> 6, lane = tid & 63;
  __shared__ float4 Ls4[256], Us4[256];
  const float4* Lg = (const float4*)(logits + b * CC);
  const float4* Ug = (const float4*)(u + b * CC);
  if (tid < 250) { Ls4[tid] = Lg[tid]; Us4[tid] = Ug[tid]; }
  else { Ls4[tid] = float4{0.f,0.f,0.f,0.f}; Us4[tid] = float4{0.f,0.f,0.f,0.f}; }
  __syncthreads();
  const float en2 = En2[b], gn2b = Gn2[b];
  const float* Usf = (const float*)Us4;
  for (int jj = 0; jj < 16; ++jj) {
    int j = jb * 64 + w * 16 + jj;
    if (j >= CC) break;                         // uniform per wave
    float zn2 = An2[j] - 2.0f * AE[b * CC + j] + en2;
    float gn2 = gn2b - 2.0f * Usf[j] + Vd[j];
    float sj = (EPSA * sqrtf(zn2)) / sqrtf(gn2);
    float best = -3.402823466e38f; int bi = 0;
    const float4* Vr = (const float4*)(V + (size_t)j * 1024);
    #pragma unroll
    for (int it = 0; it < 4; ++it) {
      int idx = it * 64 + lane;
      int c0 = idx * 4;
      float4 vv = Vr[idx];
      float4 l4 = Ls4[idx];
      float4 u4 = Us4[idx];
      float vals[4] = { l4.x + sj * (u4.x - vv.x),
                        l4.y + sj * (u4.y - vv.y),
                        l4.z + sj * (u4.z - vv.z),
                        l4.w + sj * (u4.w - vv.w) };
      #pragma unroll
      for (int comp = 0; comp < 4; ++comp) {
        int c = c0 + comp;
        if (c < CC && vals[comp] > best) { best = vals[comp]; bi = c; }
      }
    }
    #pragma unroll
    for (int o = 1; o < 64; o <<= 1) {
      float ov = __shfl_xor(best, o);
      int   oi = __shfl_xor(bi, o);
      if (ov > best || (ov == best && oi < bi)) { best = ov; bi = oi; }
    }
    if (lane == 0) pm[b * CC + j] = bi;
  }
}

// ---------------------------------------------------------------- counts + all(counts < 3)
__global__ __launch_bounds__(256) void counts_kernel(const int* __restrict__ pm,
                                                     const int* __restrict__ pred,
                                                     float* __restrict__ out) {
  int b = blockIdx.x, t = threadIdx.x;
  __shared__ int cnt[CC];
  __shared__ int bad;
  for (int c = t; c < CC; c += 256) cnt[c] = 0;
  if (t == 0) bad = 0;
  __syncthreads();
  if (t == 0) atomicAdd(&cnt[pred[b]], 1);
  for (int j = t; j < CC; j += 256) atomicAdd(&cnt[pm[b * CC + j]], 1);
  __syncthreads();
  for (int c = t; c < CC; c += 256) if (cnt[c] >= NSIM) bad = 1;
  __syncthreads();
  if (t == 0) out[b] = bad ? 0.0f : 1.0f;
}

// ---------------------------------------------------------------- launch
extern "C" void kernel_launch(void* const* d_in, const int* in_sizes, int n_in,
                              void* d_out, int out_size, void* d_ws, size_t ws_size,
                              hipStream_t stream) {
  const float* x       = (const float*)d_in[0];
  const float* W_emb   = (const float*)d_in[1];
  const float* b_emb   = (const float*)d_in[2];
  const float* W_fc    = (const float*)d_in[3];
  const float* b_fc    = (const float*)d_in[4];
  const float* anchors = (const float*)d_in[5];
  float* out = (float*)d_out;

  // workspace carve (~7.4 MB), all 16B-aligned
  float* emb    = (float*)d_ws;               // 64*768
  float* logits = emb + BB * DD;              // 64*1000
  float* p      = logits + BB * CC;           // 64*1000
  float* G      = p + BB * CC;                // 64*768
  float* u      = G + BB * DD;                // 64*1000
  float* AE     = u + BB * CC;                // 64*1000
  float* An2    = AE + BB * CC;               // 1024
  float* Vd     = An2 + 1024;                 // 1024
  float* En2    = Vd + 1024;                  // 64
  float* Gn2    = En2 + 64;                   // 64
  int*   pred   = (int*)(Gn2 + 64);           // 64
  int*   pm     = pred + 64;                  // 64*1000
  short* Bp     = (short*)(pm + BB * CC);     // 98304*8 bf16 bits (1.57 MB)
  float* V      = (float*)(Bp + 64 * 24 * 64 * 8);  // 1024*1024 f32 (4 MB)

  hipLaunchKernelGGL(pack_W_kernel,  dim3(384), dim3(256), 0, stream, W_fc, Bp);
  hipLaunchKernelGGL(V_kernel,       dim3(16, 16), dim3(256), 0, stream, Bp, V);
  hipLaunchKernelGGL(norms_jc_kernel,dim3(250), dim3(256), 0, stream, anchors, W_fc, An2, Vd);
  hipLaunchKernelGGL(emb_kernel,     dim3(BB, 3), dim3(256), 0, stream, x, W_emb, b_emb, emb);
  hipLaunchKernelGGL(logits_kernel,  dim3(BB, 4), dim3(256), 0, stream, emb, W_fc, b_fc, logits);
  hipLaunchKernelGGL(AE_kernel,      dim3(BB, 4), dim3(256), 0, stream, emb, anchors, AE);
  hipLaunchKernelGGL(softmax_kernel, dim3(BB),    dim3(256), 0, stream, logits, p, pred);
  hipLaunchKernelGGL(G_kernel,       dim3(BB, 3), dim3(256), 0, stream, p, W_fc, G);
  hipLaunchKernelGGL(u_kernel,       dim3(BB, 4), dim3(256), 0, stream, G, W_fc, u);
  hipLaunchKernelGGL(normsB_kernel,  dim3(BB),    dim3(256), 0, stream, emb, G, En2, Gn2);
  hipLaunchKernelGGL(scan_kernel,    dim3(BB, 16), dim3(256), 0, stream,
                     logits, u, AE, An2, Vd, En2, Gn2, V, pm);
  hipLaunchKernelGGL(counts_kernel,  dim3(BB), dim3(256), 0, stream, pm, pred, out);
}

// Round 7
// 198.099 us; speedup vs baseline: 8.6804x; 1.3568x over previous
//
#include <hip/hip_runtime.h>
#include <stdint.h>
#include <stddef.h>

#define BB 64
#define DIN 1024
#define DD 768
#define CC 1000
#define EPSA 0.1f
#define NSIM 3

typedef short  s16x8 __attribute__((ext_vector_type(8)));
typedef float  f32x4 __attribute__((ext_vector_type(4)));

static __device__ __forceinline__ unsigned short f2bf_rne(float x) {
  unsigned u = __float_as_uint(x);
  return (unsigned short)((u + 0x7FFFu + ((u >> 16) & 1u)) >> 16);
}

// ---------------------------------------------------------------- W_fc -> bf16 packed in MFMA frag order
// Bp[nt][ks][lane][reg]: row = nt*16 + (lane&15), k = ks*32 + (lane>>4)*8 + reg
__global__ __launch_bounds__(256) void pack_W_kernel(const float* __restrict__ W_fc,
                                                     short* __restrict__ Bp) {
  int gid = blockIdx.x * 256 + threadIdx.x;     // 64*24*64 = 98304
  if (gid >= 64 * 24 * 64) return;
  int lane = gid & 63;
  int ks   = (gid >> 6) % 24;
  int nt   = gid / (64 * 24);
  int c  = nt * 16 + (lane & 15);
  int k0 = ks * 32 + (lane >> 4) * 8;
  s16x8 vh;
  #pragma unroll
  for (int r = 0; r < 8; ++r) {
    float w = (c < CC) ? W_fc[(size_t)c * DD + k0 + r] : 0.0f;
    vh[r] = (short)f2bf_rne(w);
  }
  ((s16x8*)Bp)[gid] = vh;
}

// ---------------------------------------------------------------- V = W_fc @ W_fc^T  [1024,1024] (bf16 MFMA, fp32 out)
__global__ __launch_bounds__(256) void V_kernel(const short* __restrict__ Bp,
                                                float* __restrict__ V) {
  const int tid = threadIdx.x;
  const int w = tid >> 6, lane = tid & 63;
  const int rnt = blockIdx.x * 4 + w;       // rows rnt*16..+15
  const int cb  = blockIdx.y;               // cols cb*64..+63
  const s16x8* BH = (const s16x8*)Bp;
  f32x4 acc[4] = {};
  for (int ks = 0; ks < 24; ++ks) {
    s16x8 a = BH[(rnt * 24 + ks) * 64 + lane];
    #pragma unroll
    for (int nf = 0; nf < 4; ++nf) {
      s16x8 bf = BH[((cb * 4 + nf) * 24 + ks) * 64 + lane];
      acc[nf] = __builtin_amdgcn_mfma_f32_16x16x32_bf16(a, bf, acc[nf], 0, 0, 0);
    }
  }
  const int r0 = rnt * 16 + (lane >> 4) * 4;   // C/D: row=(lane>>4)*4+reg, col=lane&15 [m89]
  const int c0 = cb * 64 + (lane & 15);
  #pragma unroll
  for (int nf = 0; nf < 4; ++nf)
    #pragma unroll
    for (int rr = 0; rr < 4; ++rr)
      V[(size_t)(r0 + rr) * 1024 + c0 + nf * 16] = acc[nf][rr];
}

// ---------------------------------------------------------------- An2[j] = ||anchors_j||^2 (fp32)
__global__ __launch_bounds__(256) void An2_kernel(const float* __restrict__ anchors,
                                                  float* __restrict__ An2) {
  int w = threadIdx.x >> 6, lane = threadIdx.x & 63;
  int j = blockIdx.x * 4 + w;               // grid 250 -> j < 1000
  const float4* ar = (const float4*)(anchors + (size_t)j * DD);
  float an = 0.f;
  for (int k4 = lane; k4 < DD / 4; k4 += 64) {
    float4 a = ar[k4];
    an += a.x*a.x + a.y*a.y + a.z*a.z + a.w*a.w;
  }
  #pragma unroll
  for (int o = 1; o < 64; o <<= 1) an += __shfl_xor(an, o);
  if (lane == 0) An2[j] = an;
}

// ---------------------------------------------------------------- emb = x @ W_emb^T + b_emb   [64,768]
__global__ __launch_bounds__(256) void emb_kernel(const float* __restrict__ x,
                                                  const float* __restrict__ W_emb,
                                                  const float* __restrict__ b_emb,
                                                  float* __restrict__ emb) {
  int b = blockIdx.x;
  int d = blockIdx.y * 256 + threadIdx.x;
  __shared__ float xs[DIN];
  for (int k = threadIdx.x; k < DIN; k += 256) xs[k] = x[b * DIN + k];
  __syncthreads();
  const float4* wr = (const float4*)(W_emb + (size_t)d * DIN);
  float acc = 0.f;
  #pragma unroll 4
  for (int k4 = 0; k4 < DIN / 4; ++k4) {
    float4 w = wr[k4];
    acc += xs[4*k4+0]*w.x + xs[4*k4+1]*w.y + xs[4*k4+2]*w.z + xs[4*k4+3]*w.w;
  }
  emb[b * DD + d] = acc + b_emb[d];
}

// ---------------------------------------------------------------- logits + AE + En2 (fused; shares emb staging)
__global__ __launch_bounds__(256) void logitsAE_kernel(const float* __restrict__ emb,
                                                       const float* __restrict__ W_fc,
                                                       const float* __restrict__ anchors,
                                                       const float* __restrict__ b_fc,
                                                       float* __restrict__ logits,
                                                       float* __restrict__ AE,
                                                       float* __restrict__ En2) {
  int b = blockIdx.x;
  int y = blockIdx.y;
  int c = y * 256 + threadIdx.x;
  __shared__ __attribute__((aligned(16))) float es[DD];
  for (int k = threadIdx.x; k < DD; k += 256) es[k] = emb[b * DD + k];
  __syncthreads();

  if (y == 0) {   // En2[b] (block-uniform branch)
    float pe = 0.f;
    for (int k = threadIdx.x; k < DD; k += 256) pe += es[k] * es[k];
    #pragma unroll
    for (int o = 1; o < 64; o <<= 1) pe += __shfl_xor(pe, o);
    __shared__ float se[4];
    if ((threadIdx.x & 63) == 0) se[threadIdx.x >> 6] = pe;
    __syncthreads();
    if (threadIdx.x == 0) En2[b] = se[0] + se[1] + se[2] + se[3];
  }

  if (c >= CC) return;
  const float4* wr = (const float4*)(W_fc + (size_t)c * DD);
  const float4* ar = (const float4*)(anchors + (size_t)c * DD);
  float accL = 0.f, accA = 0.f;
  #pragma unroll 4
  for (int k4 = 0; k4 < DD / 4; ++k4) {
    float4 w = wr[k4];
    float4 a = ar[k4];
    float e0 = es[4*k4+0], e1 = es[4*k4+1], e2 = es[4*k4+2], e3 = es[4*k4+3];
    accL += e0*w.x + e1*w.y + e2*w.z + e3*w.w;
    accA += e0*a.x + e1*a.y + e2*a.z + e3*a.w;
  }
  logits[b * CC + c] = accL + b_fc[c];
  AE[b * CC + c]     = accA;
}

// ---------------------------------------------------------------- softmax + argmax(logits)
__global__ __launch_bounds__(256) void softmax_kernel(const float* __restrict__ logits,
                                                      float* __restrict__ p,
                                                      int* __restrict__ pred) {
  int b = blockIdx.x, t = threadIdx.x;
  __shared__ float smax[256];
  __shared__ int   sidx[256];
  __shared__ float ssum[256];
  float m = -3.402823466e38f; int mi = 0;
  for (int c = t; c < CC; c += 256) {
    float v = logits[b * CC + c];
    if (v > m) { m = v; mi = c; }
  }
  smax[t] = m; sidx[t] = mi;
  __syncthreads();
  for (int o = 128; o > 0; o >>= 1) {
    if (t < o) {
      float v2 = smax[t + o]; int i2 = sidx[t + o];
      if (v2 > smax[t] || (v2 == smax[t] && i2 < sidx[t])) { smax[t] = v2; sidx[t] = i2; }
    }
    __syncthreads();
  }
  float M = smax[0];
  if (t == 0) pred[b] = sidx[0];
  float sum = 0.f;
  for (int c = t; c < CC; c += 256) sum += expf(logits[b * CC + c] - M);
  ssum[t] = sum;
  __syncthreads();
  for (int o = 128; o > 0; o >>= 1) {
    if (t < o) ssum[t] += ssum[t + o];
    __syncthreads();
  }
  float S = ssum[0];
  for (int c = t; c < CC; c += 256) p[b * CC + c] = expf(logits[b * CC + c] - M) / S;
}

// ---------------------------------------------------------------- u[b,c] = sum_j p[b,j] * V[c,j]  (V symmetric -> row-contiguous)
__global__ __launch_bounds__(256) void u_kernel(const float* __restrict__ p,
                                                const float* __restrict__ V,
                                                float* __restrict__ u) {
  int b = blockIdx.x;
  int c = blockIdx.y * 256 + threadIdx.x;
  __shared__ __attribute__((aligned(16))) float4 ps4[256];
  if (threadIdx.x < 250) ps4[threadIdx.x] = ((const float4*)(p + b * CC))[threadIdx.x];
  else ps4[threadIdx.x] = float4{0.f, 0.f, 0.f, 0.f};
  __syncthreads();
  if (c >= CC) return;
  const float4* Vr = (const float4*)(V + (size_t)c * 1024);
  float acc = 0.f;
  #pragma unroll 4
  for (int j4 = 0; j4 < 250; ++j4) {
    float4 v = Vr[j4];
    float4 pp = ps4[j4];
    acc += pp.x*v.x + pp.y*v.y + pp.z*v.z + pp.w*v.w;
  }
  u[b * CC + c] = acc;
}

// ---------------------------------------------------------------- scan: per (b,j) argmax_c of logits[c] + s_j*(u[c] - V[j,c])
// s_j from norm algebra; Gn2 computed block-locally as p.u; Vd[j] = V[j,j].
__global__ __launch_bounds__(256) void scan_kernel(const float* __restrict__ logits,
                                                   const float* __restrict__ u,
                                                   const float* __restrict__ p,
                                                   const float* __restrict__ AE,
                                                   const float* __restrict__ An2,
                                                   const float* __restrict__ En2,
                                                   const float* __restrict__ V,
                                                   int* __restrict__ pm) {
  const int b = blockIdx.x, jb = blockIdx.y;
  const int tid = threadIdx.x, w = tid >> 6, lane = tid & 63;
  __shared__ __attribute__((aligned(16))) float4 Ls4[256], Us4[256];
  __shared__ float se[4];
  __shared__ float sGn2;
  const float4* Lg = (const float4*)(logits + b * CC);
  const float4* Ug = (const float4*)(u + b * CC);
  float part = 0.f;
  if (tid < 250) {
    float4 l4 = Lg[tid], u4 = Ug[tid];
    float4 p4 = ((const float4*)(p + b * CC))[tid];
    Ls4[tid] = l4; Us4[tid] = u4;
    part = p4.x*u4.x + p4.y*u4.y + p4.z*u4.z + p4.w*u4.w;
  } else {
    Ls4[tid] = float4{0.f,0.f,0.f,0.f};
    Us4[tid] = float4{0.f,0.f,0.f,0.f};
  }
  #pragma unroll
  for (int o = 1; o < 64; o <<= 1) part += __shfl_xor(part, o);
  if (lane == 0) se[w] = part;
  __syncthreads();
  if (tid == 0) sGn2 = se[0] + se[1] + se[2] + se[3];
  __syncthreads();

  const float en2 = En2[b], gn2b = sGn2;
  const float* Usf = (const float*)Us4;
  for (int jj = 0; jj < 16; ++jj) {
    int j = jb * 64 + w * 16 + jj;
    if (j >= CC) break;                         // uniform per wave
    float zn2 = An2[j] - 2.0f * AE[b * CC + j] + en2;
    float gn2 = gn2b - 2.0f * Usf[j] + V[(size_t)j * 1024 + j];
    float sj = (EPSA * sqrtf(zn2)) / sqrtf(gn2);
    float best = -3.402823466e38f; int bi = 0;
    const float4* Vr = (const float4*)(V + (size_t)j * 1024);
    #pragma unroll
    for (int it = 0; it < 4; ++it) {
      int idx = it * 64 + lane;
      int c0 = idx * 4;
      float4 vv = Vr[idx];
      float4 l4 = Ls4[idx];
      float4 u4 = Us4[idx];
      float vals[4] = { l4.x + sj * (u4.x - vv.x),
                        l4.y + sj * (u4.y - vv.y),
                        l4.z + sj * (u4.z - vv.z),
                        l4.w + sj * (u4.w - vv.w) };
      #pragma unroll
      for (int comp = 0; comp < 4; ++comp) {
        int c = c0 + comp;
        if (c < CC && vals[comp] > best) { best = vals[comp]; bi = c; }
      }
    }
    #pragma unroll
    for (int o = 1; o < 64; o <<= 1) {
      float ov = __shfl_xor(best, o);
      int   oi = __shfl_xor(bi, o);
      if (ov > best || (ov == best && oi < bi)) { best = ov; bi = oi; }
    }
    if (lane == 0) pm[b * CC + j] = bi;
  }
}

// ---------------------------------------------------------------- counts + all(counts < 3)
__global__ __launch_bounds__(256) void counts_kernel(const int* __restrict__ pm,
                                                     const int* __restrict__ pred,
                                                     float* __restrict__ out) {
  int b = blockIdx.x, t = threadIdx.x;
  __shared__ int cnt[CC];
  __shared__ int bad;
  for (int c = t; c < CC; c += 256) cnt[c] = 0;
  if (t == 0) bad = 0;
  __syncthreads();
  if (t == 0) atomicAdd(&cnt[pred[b]], 1);
  for (int j = t; j < CC; j += 256) atomicAdd(&cnt[pm[b * CC + j]], 1);
  __syncthreads();
  for (int c = t; c < CC; c += 256) if (cnt[c] >= NSIM) bad = 1;
  __syncthreads();
  if (t == 0) out[b] = bad ? 0.0f : 1.0f;
}

// ---------------------------------------------------------------- launch
extern "C" void kernel_launch(void* const* d_in, const int* in_sizes, int n_in,
                              void* d_out, int out_size, void* d_ws, size_t ws_size,
                              hipStream_t stream) {
  const float* x       = (const float*)d_in[0];
  const float* W_emb   = (const float*)d_in[1];
  const float* b_emb   = (const float*)d_in[2];
  const float* W_fc    = (const float*)d_in[3];
  const float* b_fc    = (const float*)d_in[4];
  const float* anchors = (const float*)d_in[5];
  float* out = (float*)d_out;

  // workspace carve (~7.0 MB), all 16B-aligned
  float* emb    = (float*)d_ws;               // 64*768
  float* logits = emb + BB * DD;              // 64*1000
  float* p      = logits + BB * CC;           // 64*1000
  float* u      = p + BB * CC;                // 64*1000
  float* AE     = u + BB * CC;                // 64*1000
  float* An2    = AE + BB * CC;               // 1024
  float* En2    = An2 + 1024;                 // 64
  int*   pred   = (int*)(En2 + 64);           // 64
  int*   pm     = pred + 64;                  // 64*1000
  short* Bp     = (short*)(pm + BB * CC);     // 98304*8 bf16 bits (1.57 MB)
  float* V      = (float*)(Bp + 64 * 24 * 64 * 8);  // 1024*1024 f32 (4 MB)

  hipLaunchKernelGGL(pack_W_kernel,  dim3(384), dim3(256), 0, stream, W_fc, Bp);
  hipLaunchKernelGGL(V_kernel,       dim3(16, 16), dim3(256), 0, stream, Bp, V);
  hipLaunchKernelGGL(An2_kernel,     dim3(250), dim3(256), 0, stream, anchors, An2);
  hipLaunchKernelGGL(emb_kernel,     dim3(BB, 3), dim3(256), 0, stream, x, W_emb, b_emb, emb);
  hipLaunchKernelGGL(logitsAE_kernel,dim3(BB, 4), dim3(256), 0, stream,
                     emb, W_fc, anchors, b_fc, logits, AE, En2);
  hipLaunchKernelGGL(softmax_kernel, dim3(BB),    dim3(256), 0, stream, logits, p, pred);
  hipLaunchKernelGGL(u_kernel,       dim3(BB, 4), dim3(256), 0, stream, p, V, u);
  hipLaunchKernelGGL(scan_kernel,    dim3(BB, 16), dim3(256), 0, stream,
                     logits, u, p, AE, An2, En2, V, pm);
  hipLaunchKernelGGL(counts_kernel,  dim3(BB), dim3(256), 0, stream, pm, pred, out);
}